// Round 6
// baseline (378.324 us; speedup 1.0000x reference)
//
#include <hip/hip_runtime.h>

#define FDIM 256
#define HDIM 32
#define D1   512
#define ADIM 64
#define BKT_SHIFT 9
#define BKT_NODES 512
#define CAP 12288          // edges per bucket incl. padding (mean 8163 + pad <= ~1800)

typedef __bf16 bf16x8 __attribute__((ext_vector_type(8)));
typedef float  f32x4  __attribute__((ext_vector_type(4)));

__device__ __forceinline__ float bf2f(unsigned short h){
  unsigned int u = ((unsigned int)h) << 16;
  return __builtin_bit_cast(float, u);
}
__device__ __forceinline__ unsigned short f2bf(float f){
  unsigned int u = __builtin_bit_cast(unsigned int, f);
  u = u + 0x7fff + ((u >> 16) & 1u);   // RNE
  return (unsigned short)(u >> 16);
}
// pack two floats to bf16x2, round-half-up (cheap)
__device__ __forceinline__ unsigned int pk2(float a, float b){
  unsigned int ua = __builtin_bit_cast(unsigned int, a) + 0x8000u;
  unsigned int ub = __builtin_bit_cast(unsigned int, b) + 0x8000u;
  return (ua >> 16) | (ub & 0xffff0000u);
}

// ---------------- weight prep (+ bkcur zero) ----------------
__device__ __forceinline__ void prep_one(int i, const float* __restrict__ src,
                                         unsigned short* __restrict__ dst,
                                         int nnt, int ld, int ncols){
  int j = i & 7; int L = (i >> 3) & 63; int t = i >> 9;
  int nt = t % nnt; int kb = t / nnt;
  int k = kb*32 + ((L >> 4) * 8) + j;
  int n = nt*16 + (L & 15);
  float v = (n < ncols) ? src[k*ld + n] : 0.f;
  dst[i] = f2bf(v);
}

__global__ void k_prep(const float* W1, const float* pW1, const float* vW1,
                       const float* pW2,
                       unsigned short* W1P, unsigned short* pW1P,
                       unsigned short* vW1P, unsigned short* pW2P,
                       int* bkcur){
  int i = blockIdx.x*256 + threadIdx.x;
  if (i < 256)  { bkcur[i] = 0;                          return; } i -= 256;
  if (i < 8192) { prep_one(i, W1,  W1P,  2, 32, 32);     return; } i -= 8192;
  if (i < 16384){ prep_one(i, pW1, pW1P, 32, 512, 512);  return; } i -= 16384;
  if (i < 16384){ prep_one(i, vW1, vW1P, 32, 512, 512);  return; } i -= 16384;
  if (i < 32768){ prep_one(i, pW2, pW2P, 4, 64, 64);     return; }
}

// ---------------- binned CSR build ----------------
// multisplit into fixed-capacity buckets; packed entry = (dst&511)<<17 | src (src<2^17)
__global__ __launch_bounds__(256) void k_stage(const int* __restrict__ src,
                                               const int* __restrict__ dst,
                                               int* __restrict__ bkcur,
                                               unsigned int* __restrict__ stage, int e){
  __shared__ int h[256], base[256], cur[256];
  int t = threadIdx.x;
  h[t] = 0; cur[t] = 0;
  __syncthreads();
  int lo = blockIdx.x*8192, hi = min(e, lo + 8192);
  for (int i = lo + t; i < hi; i += 256)
    atomicAdd(&h[dst[i] >> BKT_SHIFT], 1);
  __syncthreads();
  if (h[t] > 0) base[t] = t*CAP + atomicAdd(&bkcur[t], h[t]);
  __syncthreads();
  for (int i = lo + t; i < hi; i += 256){
    int d = dst[i]; int b = d >> BKT_SHIFT;
    int r = atomicAdd(&cur[b], 1);
    int idx = base[b] + r;
    if (idx < (b+1)*CAP)                 // overflow guard (statistically never)
      stage[idx] = ((unsigned int)(d & (BKT_NODES-1)) << 17) | (unsigned int)src[i];
  }
}

// per-bucket fine pass: node counts -> dinv/rowptr/rowend (padded to x8), scatter col,
// fill pad slots with dummy node n (zero row).
__global__ __launch_bounds__(256) void k_fine(const unsigned int* __restrict__ stage,
                                              const int* __restrict__ bkcur,
                                              int* __restrict__ rowptr,
                                              int* __restrict__ rowend,
                                              int* __restrict__ col,
                                              float* __restrict__ dinv, int n){
  __shared__ int h[512], ofs[512], s[256];
  int b = blockIdx.x, t = threadIdx.x;
  int e0 = b*CAP;
  int cnt = min(bkcur[b], CAP);
  int nb0 = b << BKT_SHIFT;
  h[t] = 0; h[t+256] = 0; __syncthreads();
  for (int i = e0 + t; i < e0 + cnt; i += 256)
    atomicAdd(&h[stage[i] >> 17], 1);
  __syncthreads();
  int a0 = h[2*t], a1 = h[2*t+1];
  int p0 = (a0 + 7) & ~7, p1 = (a1 + 7) & ~7;     // padded lengths
  int v = p0 + p1;
  s[t] = v; __syncthreads();
  for (int off = 1; off < 256; off <<= 1){
    int tv = (t >= off) ? s[t-off] : 0; __syncthreads();
    s[t] += tv; __syncthreads();
  }
  int ex = s[t] - v;
  ofs[2*t] = ex; ofs[2*t+1] = ex + p0;
  int node0 = nb0 + 2*t, node1 = node0 + 1;
  if (node0 < n){
    rowptr[node0] = e0 + ex;       rowend[node0] = e0 + min(ex + p0, CAP);
    dinv[node0] = rsqrtf((float)(a0 + 1));
  }
  if (node1 < n){
    rowptr[node1] = e0 + min(ex + p0, CAP);  rowend[node1] = e0 + min(ex + p0 + p1, CAP);
    dinv[node1] = rsqrtf((float)(a1 + 1));
  }
  __syncthreads();
  for (int i = e0 + t; i < e0 + cnt; i += 256){
    unsigned int u = stage[i];
    int r = atomicAdd(&ofs[(int)(u >> 17)], 1);
    if (r < CAP) col[e0 + r] = (int)(u & 0x1FFFF);
  }
  __syncthreads();
  {
    int st0 = ofs[2*t];
    for (int j = st0; j < ex + p0 && j < CAP; ++j) col[e0 + j] = n;
    int st1 = ofs[2*t+1];
    for (int j = st1; j < ex + p0 + p1 && j < CAP; ++j) col[e0 + j] = n;
  }
}

// ---------------- gemm1: x1' = bf16((features @ W1) * dinv[row]); row n := 0 ----------------
__global__ __launch_bounds__(256) void k_gemm1(const float* __restrict__ feat,
                                               const unsigned short* __restrict__ W1P,
                                               const float* __restrict__ dinv,
                                               unsigned short* __restrict__ x1, int n){
  int lane = threadIdx.x & 63; int wv = threadIdx.x >> 6;
  int lid = lane & 15, quad = lane >> 4;
  int base = (blockIdx.x*4 + wv) * 16;
  int row = base + lid; if (row >= n) row = n - 1;
  const float* fr = feat + (size_t)row * FDIM;
  f32x4 acc0 = {0.f,0.f,0.f,0.f}, acc1 = {0.f,0.f,0.f,0.f};
#pragma unroll
  for (int kb = 0; kb < 8; ++kb){
    float4 fa = *(const float4*)(fr + kb*32 + quad*8);
    float4 fb = *(const float4*)(fr + kb*32 + quad*8 + 4);
    bf16x8 bfr;
    bfr[0]=(__bf16)fa.x; bfr[1]=(__bf16)fa.y; bfr[2]=(__bf16)fa.z; bfr[3]=(__bf16)fa.w;
    bfr[4]=(__bf16)fb.x; bfr[5]=(__bf16)fb.y; bfr[6]=(__bf16)fb.z; bfr[7]=(__bf16)fb.w;
    bf16x8 w0 = *(const bf16x8*)(W1P + (size_t)((kb*2+0)*64 + lane)*8);
    bf16x8 w1 = *(const bf16x8*)(W1P + (size_t)((kb*2+1)*64 + lane)*8);
    acc0 = __builtin_amdgcn_mfma_f32_16x16x32_bf16(w0, bfr, acc0, 0,0,0);
    acc1 = __builtin_amdgcn_mfma_f32_16x16x32_bf16(w1, bfr, acc1, 0,0,0);
  }
  int orow = base + lid;
  if (orow <= n){
    float di = (orow < n) ? dinv[orow] : 0.f;    // row n -> zeros
    unsigned short* o = x1 + (size_t)orow*HDIM;
    uint2 q0, q1;
    q0.x = f2bf(acc0[0]*di) | ((unsigned)f2bf(acc0[1]*di)<<16);
    q0.y = f2bf(acc0[2]*di) | ((unsigned)f2bf(acc0[3]*di)<<16);
    q1.x = f2bf(acc1[0]*di) | ((unsigned)f2bf(acc1[1]*di)<<16);
    q1.y = f2bf(acc1[2]*di) | ((unsigned)f2bf(acc1[3]*di)<<16);
    *(uint2*)(o + quad*4)      = q0;
    *(uint2*)(o + 16 + quad*4) = q1;
  }
}

// ---------------- conv: padded edge lists, single fast path ----------------
// FUSE_W2=1 (layer 1): out = bf16(dinv * (relu(conv+b) @ W2))  -- h1 never materialized
// FUSE_W2=0 (layer 2): out = bf16(relu(conv*dinv + b))
template<int FUSE_W2>
__global__ __launch_bounds__(256) void k_conv(const unsigned short* __restrict__ x,
                                              const float* __restrict__ dinv,
                                              const int* __restrict__ rowptr,
                                              const int* __restrict__ rowend,
                                              const int* __restrict__ col,
                                              const float* __restrict__ bias,
                                              const float* __restrict__ W2,
                                              unsigned short* __restrict__ y, int n){
  __shared__ float W2s[FUSE_W2 ? 1024 : 1];
  __shared__ float yrow[4][32];
  int t = threadIdx.x;
  if (FUSE_W2){
    for (int j = t; j < 1024; j += 256) W2s[j] = W2[j];
    __syncthreads();                      // all 256 threads reach this
  }
  int gid = (blockIdx.x*256 + t) >> 6;    // one wave per node
  int node = (gid < n) ? gid : n - 1;
  int lane = t & 63;
  int c = lane & 31, eh = lane >> 5, wv = t >> 6;
  float acc = (eh == 0) ? bf2f(x[(size_t)node*HDIM + c]) : 0.f;  // self-loop (pre-scaled)
  int rp = rowptr[node], re = rowend[node];
  int nb8 = (re - rp) >> 3;
  int jb = rp + (eh << 2);
#pragma clang loop unroll_count(2)
  for (int it = 0; it < nb8; ++it, jb += 8){
    int c0 = col[jb+0], c1 = col[jb+1], c2 = col[jb+2], c3 = col[jb+3];
    float v0 = bf2f(x[(size_t)c0*HDIM + c]);
    float v1 = bf2f(x[(size_t)c1*HDIM + c]);
    float v2 = bf2f(x[(size_t)c2*HDIM + c]);
    float v3 = bf2f(x[(size_t)c3*HDIM + c]);
    acc += (v0 + v1) + (v2 + v3);
  }
  acc += __shfl_xor(acc, 32);
  float di = dinv[node];
  if (FUSE_W2){
    // y_k = relu(acc*di + b1[k]) ; out[c] = di * sum_k y_k * W2[k][c]
    if (eh == 0) yrow[wv][c] = fmaxf(acc * di + bias[c], 0.f);
    float a = 0.f;
#pragma unroll
    for (int k = 0; k < 16; ++k){
      int kk = eh*16 + k;
      a += yrow[wv][kk] * W2s[kk*32 + c];
    }
    a += __shfl_xor(a, 32);
    if (eh == 0 && gid < n)
      y[(size_t)node*HDIM + c] = f2bf(a * di);
  } else {
    if (eh == 0 && gid < n){
      float v = acc * di + bias[c];
      y[(size_t)node*HDIM + c] = f2bf(fmaxf(v, 0.f));
    }
  }
}

// ---------------- fused heads: 32 nodes/wave, weight loads shared by 2 groups ----------------
#define TSTR 56
__global__ __launch_bounds__(256, 4) void k_head(const unsigned short* __restrict__ h,
    const unsigned short* __restrict__ pW1P, const unsigned short* __restrict__ pW2P,
    const unsigned short* __restrict__ vW1P, const float* __restrict__ vW2,
    const float* __restrict__ pb1, const float* __restrict__ pb2,
    const float* __restrict__ vb1, const float* __restrict__ vb2,
    float* __restrict__ pol, float* __restrict__ val, int n){
  __shared__ unsigned short lds[4*2*16*TSTR];       // per wave: 2 groups x 16 x TSTR
  int lane = threadIdx.x & 63; int wv = threadIdx.x >> 6;
  int lid = lane & 15, quad = lane >> 4;
  int nbase = (blockIdx.x*4 + wv) * 32;
  unsigned short* tb0 = lds + wv*(2*16*TSTR);
  unsigned short* tb1 = tb0 + 16*TSTR;
  int r0 = nbase + lid;      if (r0 >= n) r0 = n - 1;
  int r1 = nbase + 16 + lid; if (r1 >= n) r1 = n - 1;
  bf16x8 hf0 = *(const bf16x8*)(h + (size_t)r0*HDIM + quad*8);
  bf16x8 hf1 = *(const bf16x8*)(h + (size_t)r1*HDIM + quad*8);
  f32x4 z = {0.f,0.f,0.f,0.f};
  f32x4 acc[8] = {z,z,z,z,z,z,z,z};                 // [group][tt]

#pragma unroll 2
  for (int kb = 0; kb < 16; ++kb){
    bf16x8 w0 = *(const bf16x8*)(pW1P + (size_t)((2*kb+0)*64 + lane)*8);
    bf16x8 w1 = *(const bf16x8*)(pW1P + (size_t)((2*kb+1)*64 + lane)*8);
    f32x4 c00 = __builtin_amdgcn_mfma_f32_16x16x32_bf16(w0, hf0, z, 0,0,0);
    f32x4 c01 = __builtin_amdgcn_mfma_f32_16x16x32_bf16(w1, hf0, z, 0,0,0);
    f32x4 c10 = __builtin_amdgcn_mfma_f32_16x16x32_bf16(w0, hf1, z, 0,0,0);
    f32x4 c11 = __builtin_amdgcn_mfma_f32_16x16x32_bf16(w1, hf1, z, 0,0,0);
    float4 b0 = *(const float4*)(pb1 + (2*kb+0)*16 + quad*4);
    float4 b1 = *(const float4*)(pb1 + (2*kb+1)*16 + quad*4);
    uint2 q;
    q.x = pk2(fmaxf(c00[0]+b0.x,0.f), fmaxf(c00[1]+b0.y,0.f));
    q.y = pk2(fmaxf(c00[2]+b0.z,0.f), fmaxf(c00[3]+b0.w,0.f));
    *(uint2*)(tb0 + lid*TSTR + quad*4) = q;
    q.x = pk2(fmaxf(c01[0]+b1.x,0.f), fmaxf(c01[1]+b1.y,0.f));
    q.y = pk2(fmaxf(c01[2]+b1.z,0.f), fmaxf(c01[3]+b1.w,0.f));
    *(uint2*)(tb0 + lid*TSTR + 16 + quad*4) = q;
    q.x = pk2(fmaxf(c10[0]+b0.x,0.f), fmaxf(c10[1]+b0.y,0.f));
    q.y = pk2(fmaxf(c10[2]+b0.z,0.f), fmaxf(c10[3]+b0.w,0.f));
    *(uint2*)(tb1 + lid*TSTR + quad*4) = q;
    q.x = pk2(fmaxf(c11[0]+b1.x,0.f), fmaxf(c11[1]+b1.y,0.f));
    q.y = pk2(fmaxf(c11[2]+b1.z,0.f), fmaxf(c11[3]+b1.w,0.f));
    *(uint2*)(tb1 + lid*TSTR + 16 + quad*4) = q;
    bf16x8 a0 = *(const bf16x8*)(tb0 + lid*TSTR + quad*8);
    bf16x8 a1 = *(const bf16x8*)(tb1 + lid*TSTR + quad*8);
#pragma unroll
    for (int tt = 0; tt < 4; ++tt){
      bf16x8 b = *(const bf16x8*)(pW2P + (size_t)((kb*4+tt)*64 + lane)*8);
      acc[tt]   = __builtin_amdgcn_mfma_f32_16x16x32_bf16(a0, b, acc[tt],   0,0,0);
      acc[4+tt] = __builtin_amdgcn_mfma_f32_16x16x32_bf16(a1, b, acc[4+tt], 0,0,0);
    }
  }
#pragma unroll
  for (int g = 0; g < 2; ++g){
#pragma unroll
    for (int tt = 0; tt < 4; ++tt){
      float pb2v = pb2[tt*16 + lid];
#pragma unroll
      for (int r = 0; r < 4; ++r){
        int node = nbase + g*16 + quad*4 + r;
        if (node < n) pol[(size_t)node*ADIM + tt*16 + lid] = acc[g*4+tt][r] + pb2v;
      }
    }
  }

  float va0 = 0.f, va1 = 0.f;
#pragma unroll 4
  for (int t = 0; t < 32; ++t){
    bf16x8 a = *(const bf16x8*)(vW1P + (size_t)(t*64 + lane)*8);
    f32x4 c0 = __builtin_amdgcn_mfma_f32_16x16x32_bf16(a, hf0, z, 0,0,0);
    f32x4 c1 = __builtin_amdgcn_mfma_f32_16x16x32_bf16(a, hf1, z, 0,0,0);
    float4 b  = *(const float4*)(vb1 + t*16 + quad*4);
    float4 w2 = *(const float4*)(vW2 + t*16 + quad*4);
    va0 += fmaxf(c0[0]+b.x,0.f)*w2.x + fmaxf(c0[1]+b.y,0.f)*w2.y
         + fmaxf(c0[2]+b.z,0.f)*w2.z + fmaxf(c0[3]+b.w,0.f)*w2.w;
    va1 += fmaxf(c1[0]+b.x,0.f)*w2.x + fmaxf(c1[1]+b.y,0.f)*w2.y
         + fmaxf(c1[2]+b.z,0.f)*w2.z + fmaxf(c1[3]+b.w,0.f)*w2.w;
  }
  va0 += __shfl_xor(va0, 16); va0 += __shfl_xor(va0, 32);
  va1 += __shfl_xor(va1, 16); va1 += __shfl_xor(va1, 32);
  if (quad == 0){
    float vb = vb2[0];
    int n0 = nbase + lid, n1 = nbase + 16 + lid;
    if (n0 < n) val[n0] = va0 + vb;
    if (n1 < n) val[n1] = va1 + vb;
  }
}

extern "C" void kernel_launch(void* const* d_in, const int* in_sizes, int n_in,
                              void* d_out, int out_size, void* d_ws, size_t ws_size,
                              hipStream_t stream){
  const float* feat = (const float*)d_in[0];
  const int*   edge = (const int*)d_in[1];
  const float* W1  = (const float*)d_in[2];
  const float* b1  = (const float*)d_in[3];
  const float* W2  = (const float*)d_in[4];
  const float* b2  = (const float*)d_in[5];
  const float* pW1 = (const float*)d_in[6];
  const float* pb1 = (const float*)d_in[7];
  const float* pW2 = (const float*)d_in[8];
  const float* pb2 = (const float*)d_in[9];
  const float* vW1 = (const float*)d_in[10];
  const float* vb1 = (const float*)d_in[11];
  const float* vW2 = (const float*)d_in[12];
  const float* vb2 = (const float*)d_in[13];
  int n = in_sizes[0] / FDIM;     // 100000
  int e = in_sizes[1] / 2;        // 1600000
  int nbk = (n + BKT_NODES - 1) >> BKT_SHIFT;   // 196

  char* w = (char*)d_ws;
  auto alloc = [&](size_t bytes)->char*{
    char* p = w; w += (bytes + 255) & ~(size_t)255; return p;
  };
  size_t nodebuf = (size_t)(n+1)*HDIM*2;                      // 6.4 MB (+zero row)
  size_t stagesz = (size_t)nbk*CAP*4;                         // 9.6 MB (packed uint32)
  char* stagebuf = alloc(stagesz > 2*nodebuf ? stagesz : 2*nodebuf);
  unsigned int* stage = (unsigned int*)stagebuf;
  unsigned short* x1 = (unsigned short*)stagebuf;             // alias: stage dead after k_fine
  unsigned short* x2 = (unsigned short*)(stagebuf + nodebuf);
  unsigned short* hb = x1;                                    // x1 dead after conv1
  int*   col    = (int*)  alloc((size_t)nbk*CAP*4);
  int*   rowptr = (int*)  alloc((size_t)n*4);
  int*   rowend = (int*)  alloc((size_t)n*4);
  float* dinv   = (float*)alloc((size_t)n*4);
  int*   bkcur  = (int*)  alloc(256*4);
  unsigned short* W1P  = (unsigned short*)alloc(8192*2);
  unsigned short* pW1P = (unsigned short*)alloc(16384*2);
  unsigned short* vW1P = (unsigned short*)alloc(16384*2);
  unsigned short* pW2P = (unsigned short*)alloc(32768*2);

  int gb  = (n + 63)/64;           // 16 rows/wave kernels
  int hb2 = (n + 127)/128;         // head: 32 rows/wave, 4 waves/block

  k_prep <<<(73984 + 255)/256, 256, 0, stream>>>(W1, pW1, vW1, pW2,
                                                 W1P, pW1P, vW1P, pW2P, bkcur);
  k_stage<<<(e + 8191)/8192, 256, 0, stream>>>(edge, edge + e, bkcur, stage, e);
  k_fine <<<nbk, 256, 0, stream>>>(stage, bkcur, rowptr, rowend, col, dinv, n);
  k_gemm1<<<gb, 256, 0, stream>>>(feat, W1P, dinv, x1, n);
  k_conv<1><<<(n + 3)/4, 256, 0, stream>>>(x1, dinv, rowptr, rowend, col, b1, W2, x2, n);
  k_conv<0><<<(n + 3)/4, 256, 0, stream>>>(x2, dinv, rowptr, rowend, col, b2, nullptr, hb, n);
  float* pol = (float*)d_out;
  float* val = pol + (size_t)n*ADIM;
  k_head <<<hb2, 256, 0, stream>>>(hb, pW1P, pW2P, vW1P, vW2,
                                   pb1, pb2, vb1, vb2, pol, val, n);
}